// Round 1
// baseline (748.582 us; speedup 1.0000x reference)
//
#include <hip/hip_runtime.h>
#include <math.h>

#define B 64
#define S 2048
#define H 512

// workspace layout (floats)
#define QS_OFF 0                    // qs:     B*H
#define SC_OFF (B*H)                // scores: B*S
#define PC_OFF (B*H + B*S)          // pc:     B*NCHUNK*H
#define NCHUNK 32
#define CHUNK  64                   // S / NCHUNK

// ---------------- kernel 1: q_scores = query @ W_s (B,H) ----------------
__global__ __launch_bounds__(512) void qs_kernel(const float* __restrict__ query,
                                                 const float* __restrict__ W_s,
                                                 float* __restrict__ qs) {
    const int b = blockIdx.x, k = threadIdx.x;
    __shared__ float q[H];
    q[k] = query[b * H + k];
    __syncthreads();
    float acc = 0.f;
#pragma unroll 8
    for (int h = 0; h < H; ++h) acc = fmaf(q[h], W_s[h * H + k], acc);
    qs[b * H + k] = acc;
}

// ------- kernel 2: scores[b,s] = v . tanh(enc[b,s,:] @ W_h + qs[b,:]) -------
// 16 rows per block, 256 threads, 2 output cols per thread. Masked tiles exit.
__global__ __launch_bounds__(256) void scores_kernel(const float* __restrict__ enc,
                                                     const float* __restrict__ W_h,
                                                     const float* __restrict__ v,
                                                     const int* __restrict__ lens,
                                                     const float* __restrict__ qs,
                                                     float* __restrict__ scores) {
    const int b = blockIdx.x >> 7;
    const int s0 = (blockIdx.x & 127) * 16;
    const int len = lens[b];
    if (s0 >= len) return;
    const int t = threadIdx.x;

    __shared__ float elds[16 * H];       // 32 KB: 16 enc rows
    __shared__ float red[4][16];

    // stage 16 contiguous enc rows (16*512 floats) as float4
    const float4* src = (const float4*)(enc + (size_t)(b * S + s0) * H);
    float4* dst = (float4*)elds;
#pragma unroll
    for (int i = 0; i < 8; ++i) dst[i * 256 + t] = src[i * 256 + t];
    __syncthreads();

    float acc0[16], acc1[16];
#pragma unroll
    for (int r = 0; r < 16; ++r) { acc0[r] = 0.f; acc1[r] = 0.f; }

    for (int h4 = 0; h4 < 128; ++h4) {
        const float* wp = W_h + h4 * 4 * H + t;
        const float w00 = wp[0],       w01 = wp[H],       w02 = wp[2 * H],       w03 = wp[3 * H];
        const float w10 = wp[256],     w11 = wp[H + 256], w12 = wp[2 * H + 256], w13 = wp[3 * H + 256];
#pragma unroll
        for (int r = 0; r < 16; ++r) {
            float4 e = *(const float4*)&elds[r * H + h4 * 4];
            acc0[r] = fmaf(e.w, w03, fmaf(e.z, w02, fmaf(e.y, w01, fmaf(e.x, w00, acc0[r]))));
            acc1[r] = fmaf(e.w, w13, fmaf(e.z, w12, fmaf(e.y, w11, fmaf(e.x, w10, acc1[r]))));
        }
    }

    const float qs0 = qs[b * H + t], qs1 = qs[b * H + t + 256];
    const float v0 = v[t], v1 = v[t + 256];
    const int wave = t >> 6, lane = t & 63;
#pragma unroll
    for (int r = 0; r < 16; ++r) {
        float p = v0 * tanhf(acc0[r] + qs0) + v1 * tanhf(acc1[r] + qs1);
#pragma unroll
        for (int off = 32; off > 0; off >>= 1) p += __shfl_down(p, off);
        if (lane == 0) red[wave][r] = p;
    }
    __syncthreads();
    if (t < 16) {
        scores[b * S + s0 + t] = red[0][t] + red[1][t] + red[2][t] + red[3][t];
    }
}

// ---------------- kernel 3: masked softmax over S, write attn ----------------
__global__ __launch_bounds__(256) void softmax_kernel(const float* __restrict__ scores,
                                                      const int* __restrict__ lens,
                                                      float* __restrict__ attn) {
    const int b = blockIdx.x, t = threadIdx.x;
    const int len = lens[b];
    const int wave = t >> 6, lane = t & 63;
    __shared__ float red[4];

    float vals[8];
    float m = -INFINITY;
#pragma unroll
    for (int i = 0; i < 8; ++i) {
        const int s = i * 256 + t;
        vals[i] = (s < len) ? scores[b * S + s] : -INFINITY;
        m = fmaxf(m, vals[i]);
    }
#pragma unroll
    for (int off = 32; off > 0; off >>= 1) m = fmaxf(m, __shfl_down(m, off));
    if (lane == 0) red[wave] = m;
    __syncthreads();
    m = fmaxf(fmaxf(red[0], red[1]), fmaxf(red[2], red[3]));
    __syncthreads();

    float e[8];
    float sum = 0.f;
#pragma unroll
    for (int i = 0; i < 8; ++i) {
        const int s = i * 256 + t;
        e[i] = (s < len) ? expf(vals[i] - m) : 0.f;
        sum += e[i];
    }
#pragma unroll
    for (int off = 32; off > 0; off >>= 1) sum += __shfl_down(sum, off);
    if (lane == 0) red[wave] = sum;
    __syncthreads();
    const float inv = 1.f / (red[0] + red[1] + red[2] + red[3]);
#pragma unroll
    for (int i = 0; i < 8; ++i) attn[b * S + i * 256 + t] = e[i] * inv;
}

// -------- kernel 4a: partial context sums over s-chunks (masked skipped) --------
__global__ __launch_bounds__(256) void ctx_partial_kernel(const float* __restrict__ enc,
                                                          const float* __restrict__ attn,
                                                          const int* __restrict__ lens,
                                                          float* __restrict__ pc) {
    const int b = blockIdx.x >> 5, c = blockIdx.x & 31;
    const int len = lens[b];
    const int sbase = c * CHUNK;
    if (sbase >= len) return;
    const int ns = min(CHUNK, len - sbase);
    const int t = threadIdx.x;

    __shared__ float alds[CHUNK];
    if (t < CHUNK) alds[t] = (t < ns) ? attn[b * S + sbase + t] : 0.f;
    __syncthreads();

    const float2* e2 = (const float2*)(enc + (size_t)(b * S + sbase) * H);
    float2 acc = make_float2(0.f, 0.f);
    for (int s = 0; s < ns; ++s) {
        const float a = alds[s];
        const float2 e = e2[s * 256 + t];
        acc.x = fmaf(a, e.x, acc.x);
        acc.y = fmaf(a, e.y, acc.y);
    }
    ((float2*)(pc + (size_t)(b * NCHUNK + c) * H))[t] = acc;
}

// ------ kernel 4b: context reduce + w_out = tanh([ctx, q] @ W_out) ------
__global__ __launch_bounds__(512) void out_kernel(const float* __restrict__ pc,
                                                  const float* __restrict__ query,
                                                  const float* __restrict__ W_out,
                                                  const int* __restrict__ lens,
                                                  float* __restrict__ wout) {
    const int b = blockIdx.x, k = threadIdx.x;
    const int len = lens[b];
    const int nch = (len + CHUNK - 1) / CHUNK;
    __shared__ float cat[2 * H];
    float ctx = 0.f;
    for (int c = 0; c < nch; ++c) ctx += pc[(size_t)(b * NCHUNK + c) * H + k];
    cat[k] = ctx;
    cat[H + k] = query[b * H + k];
    __syncthreads();
    float acc = 0.f;
#pragma unroll 8
    for (int c = 0; c < 2 * H; ++c) acc = fmaf(cat[c], W_out[c * H + k], acc);
    wout[b * H + k] = tanhf(acc);
}

extern "C" void kernel_launch(void* const* d_in, const int* in_sizes, int n_in,
                              void* d_out, int out_size, void* d_ws, size_t ws_size,
                              hipStream_t stream) {
    const float* query = (const float*)d_in[0];
    const float* enc   = (const float*)d_in[1];
    const int*   lens  = (const int*)d_in[2];
    const float* W_h   = (const float*)d_in[3];
    const float* W_s   = (const float*)d_in[4];
    const float* v     = (const float*)d_in[5];
    const float* W_out = (const float*)d_in[6];

    float* out  = (float*)d_out;
    float* wout = out;          // B*H
    float* attn = out + B * H;  // B*S

    float* ws     = (float*)d_ws;
    float* qs     = ws + QS_OFF;
    float* scores = ws + SC_OFF;
    float* pc     = ws + PC_OFF;

    qs_kernel<<<B, H, 0, stream>>>(query, W_s, qs);
    scores_kernel<<<B * (S / 16), 256, 0, stream>>>(enc, W_h, v, lens, qs, scores);
    softmax_kernel<<<B, 256, 0, stream>>>(scores, lens, attn);
    ctx_partial_kernel<<<B * NCHUNK, 256, 0, stream>>>(enc, attn, lens, pc);
    out_kernel<<<B, H, 0, stream>>>(pc, query, W_out, lens, wout);
}

// Round 2
// 375.583 us; speedup vs baseline: 1.9931x; 1.9931x over previous
//
#include <hip/hip_runtime.h>
#include <math.h>

#define B 64
#define S 2048
#define H 512
#define BM 32

// workspace layout (floats)
#define QS_OFF 0                    // qs:     B*H
#define SC_OFF (B*H)                // scores: B*S
#define PC_OFF (B*H + B*S)          // pc:     B*NCHUNK*H  (Wt aliases this region, used before pc)
#define NCHUNK 32
#define CHUNK  64                   // S / NCHUNK

typedef __attribute__((ext_vector_type(8))) short short8;
typedef __attribute__((ext_vector_type(4))) float f32x4;

static __device__ __forceinline__ short f2bf(float f) {
    union { float f; unsigned u; } x; x.f = f;
    unsigned r = x.u + 0x7fffu + ((x.u >> 16) & 1u);   // RNE
    return (short)(r >> 16);
}

// ---------------- kernel 1: q_scores = query @ W_s (B,H) ----------------
__global__ __launch_bounds__(512) void qs_kernel(const float* __restrict__ query,
                                                 const float* __restrict__ W_s,
                                                 float* __restrict__ qs) {
    const int b = blockIdx.x, k = threadIdx.x;
    __shared__ float q[H];
    q[k] = query[b * H + k];
    __syncthreads();
    float acc = 0.f;
#pragma unroll 8
    for (int h = 0; h < H; ++h) acc = fmaf(q[h], W_s[h * H + k], acc);
    qs[b * H + k] = acc;
}

// -------- kernel 1b: W_h -> bf16 fragment-ordered Wt --------
// Wt[(((CB*16+kk)*4 + g)*16 + c)*8 + j] = bf16(W_h[(kk*32+g*8+j)*H + CB*16+c])
__global__ __launch_bounds__(256) void wt_prep(const float* __restrict__ W_h,
                                               short* __restrict__ Wt) {
    const int idx = blockIdx.x * 256 + threadIdx.x;       // 0 .. 262143
    const int j  = idx & 7;
    const int c  = (idx >> 3) & 15;
    const int g  = (idx >> 7) & 3;
    const int kk = (idx >> 9) & 15;
    const int CB = idx >> 13;
    const int k   = kk * 32 + g * 8 + j;
    const int col = CB * 16 + c;
    Wt[idx] = f2bf(W_h[k * H + col]);
}

// ------- kernel 2: scores[b,s] = v . tanh(enc[b,s,:] @ W_h + qs[b,:]) — MFMA -------
// 32 rows per block, 4 waves; wave w owns cols [w*128, w*128+128).
__global__ __launch_bounds__(256) void scores_mfma_kernel(const float* __restrict__ enc,
                                                          const short* __restrict__ Wt,
                                                          const float* __restrict__ v,
                                                          const int* __restrict__ lens,
                                                          const float* __restrict__ qs,
                                                          float* __restrict__ scores) {
    const int b = blockIdx.x >> 6;
    const int s0 = (blockIdx.x & 63) * BM;
    const int len = lens[b];
    if (s0 >= len) return;
    const int t = threadIdx.x;
    const int w = t >> 6, l = t & 63;
    const int g = l >> 4, c = l & 15;

    __shared__ short elds[BM * H];     // 32 KB, XOR-swizzled bf16 tile
    __shared__ float red[4][BM];

    // stage 32x512 fp32 -> bf16 into LDS (swizzled)
    {
        const float* src = enc + ((size_t)(b * S + s0)) * H;
#pragma unroll
        for (int i = 0; i < 8; ++i) {
            const int ch = i * 256 + t;
            const int row = ch >> 6;
            const int ks  = (ch & 63) * 8;
            const float4* p = (const float4*)(src + row * H + ks);
            const float4 f0 = p[0], f1 = p[1];
            short8 hv;
            hv[0] = f2bf(f0.x); hv[1] = f2bf(f0.y); hv[2] = f2bf(f0.z); hv[3] = f2bf(f0.w);
            hv[4] = f2bf(f1.x); hv[5] = f2bf(f1.y); hv[6] = f2bf(f1.z); hv[7] = f2bf(f1.w);
            const int byteoff = row * 1024 + ((ks * 2) ^ ((row & 7) << 4));
            *(short8*)((char*)elds + byteoff) = hv;
        }
    }
    __syncthreads();

    f32x4 acc[2][8];
    const f32x4 z = {0.f, 0.f, 0.f, 0.f};
#pragma unroll
    for (int rb = 0; rb < 2; ++rb)
#pragma unroll
        for (int cb = 0; cb < 8; ++cb) acc[rb][cb] = z;

    for (int kk = 0; kk < 16; ++kk) {
        // A frags: row = rb*16 + c, k = kk*32 + g*8 .. +8
        const int koff = kk * 64 + g * 16;   // byte offset within row
        const int r0 = c, r1 = 16 + c;
        const short8 a0 = *(const short8*)((char*)elds + r0 * 1024 + (koff ^ ((r0 & 7) << 4)));
        const short8 a1 = *(const short8*)((char*)elds + r1 * 1024 + (koff ^ ((r1 & 7) << 4)));
        // B frags: contiguous 16B per lane, 1KB per (CB,kk) per wave
        const short* wp = Wt + (size_t)(w * 128 + kk) * 512 + g * 128 + c * 8;
#pragma unroll
        for (int cb = 0; cb < 8; ++cb) {
            const short8 bf = *(const short8*)(wp + cb * (16 * 512));
            acc[0][cb] = __builtin_amdgcn_mfma_f32_16x16x32_bf16(a0, bf, acc[0][cb], 0, 0, 0);
            acc[1][cb] = __builtin_amdgcn_mfma_f32_16x16x32_bf16(a1, bf, acc[1][cb], 0, 0, 0);
        }
    }

    // epilogue: p[row] = sum_col v[col] * tanh(escore + qs[col])
    float part[2][4];
#pragma unroll
    for (int rb = 0; rb < 2; ++rb)
#pragma unroll
        for (int r = 0; r < 4; ++r) part[rb][r] = 0.f;

#pragma unroll
    for (int cb = 0; cb < 8; ++cb) {
        const int col = w * 128 + cb * 16 + c;
        const float vc = v[col];
        const float qc = qs[b * H + col];
#pragma unroll
        for (int rb = 0; rb < 2; ++rb)
#pragma unroll
            for (int r = 0; r < 4; ++r)
                part[rb][r] += vc * tanhf(acc[rb][cb][r] + qc);
    }
    // reduce across the 16 lanes (c) holding the same rows
#pragma unroll
    for (int m = 1; m < 16; m <<= 1)
#pragma unroll
        for (int rb = 0; rb < 2; ++rb)
#pragma unroll
            for (int r = 0; r < 4; ++r)
                part[rb][r] += __shfl_xor(part[rb][r], m);
    if (c == 0) {
#pragma unroll
        for (int rb = 0; rb < 2; ++rb)
#pragma unroll
            for (int r = 0; r < 4; ++r)
                red[w][rb * 16 + g * 4 + r] = part[rb][r];
    }
    __syncthreads();
    if (t < BM) scores[b * S + s0 + t] = red[0][t] + red[1][t] + red[2][t] + red[3][t];
}

// ---------------- kernel 3: masked softmax over S, write attn ----------------
__global__ __launch_bounds__(256) void softmax_kernel(const float* __restrict__ scores,
                                                      const int* __restrict__ lens,
                                                      float* __restrict__ attn) {
    const int b = blockIdx.x, t = threadIdx.x;
    const int len = lens[b];
    const int wave = t >> 6, lane = t & 63;
    __shared__ float red[4];

    float vals[8];
    float m = -INFINITY;
#pragma unroll
    for (int i = 0; i < 8; ++i) {
        const int s = i * 256 + t;
        vals[i] = (s < len) ? scores[b * S + s] : -INFINITY;
        m = fmaxf(m, vals[i]);
    }
#pragma unroll
    for (int off = 32; off > 0; off >>= 1) m = fmaxf(m, __shfl_down(m, off));
    if (lane == 0) red[wave] = m;
    __syncthreads();
    m = fmaxf(fmaxf(red[0], red[1]), fmaxf(red[2], red[3]));
    __syncthreads();

    float e[8];
    float sum = 0.f;
#pragma unroll
    for (int i = 0; i < 8; ++i) {
        const int s = i * 256 + t;
        e[i] = (s < len) ? expf(vals[i] - m) : 0.f;
        sum += e[i];
    }
#pragma unroll
    for (int off = 32; off > 0; off >>= 1) sum += __shfl_down(sum, off);
    if (lane == 0) red[wave] = sum;
    __syncthreads();
    const float inv = 1.f / (red[0] + red[1] + red[2] + red[3]);
#pragma unroll
    for (int i = 0; i < 8; ++i) attn[b * S + i * 256 + t] = e[i] * inv;
}

// -------- kernel 4a: partial context sums over s-chunks (masked skipped) --------
__global__ __launch_bounds__(256) void ctx_partial_kernel(const float* __restrict__ enc,
                                                          const float* __restrict__ attn,
                                                          const int* __restrict__ lens,
                                                          float* __restrict__ pc) {
    const int b = blockIdx.x >> 5, c = blockIdx.x & 31;
    const int len = lens[b];
    const int sbase = c * CHUNK;
    if (sbase >= len) return;
    const int ns = min(CHUNK, len - sbase);
    const int t = threadIdx.x;

    __shared__ float alds[CHUNK];
    if (t < CHUNK) alds[t] = (t < ns) ? attn[b * S + sbase + t] : 0.f;
    __syncthreads();

    const float2* e2 = (const float2*)(enc + (size_t)(b * S + sbase) * H);
    float2 acc = make_float2(0.f, 0.f);
    for (int s = 0; s < ns; ++s) {
        const float a = alds[s];
        const float2 e = e2[s * 256 + t];
        acc.x = fmaf(a, e.x, acc.x);
        acc.y = fmaf(a, e.y, acc.y);
    }
    ((float2*)(pc + (size_t)(b * NCHUNK + c) * H))[t] = acc;
}

// ------ kernel 4b: context reduce + w_out = tanh([ctx, q] @ W_out) ------
__global__ __launch_bounds__(512) void out_kernel(const float* __restrict__ pc,
                                                  const float* __restrict__ query,
                                                  const float* __restrict__ W_out,
                                                  const int* __restrict__ lens,
                                                  float* __restrict__ wout) {
    const int b = blockIdx.x, k = threadIdx.x;
    const int len = lens[b];
    const int nch = (len + CHUNK - 1) / CHUNK;
    __shared__ float cat[2 * H];
    float ctx = 0.f;
    for (int c = 0; c < nch; ++c) ctx += pc[(size_t)(b * NCHUNK + c) * H + k];
    cat[k] = ctx;
    cat[H + k] = query[b * H + k];
    __syncthreads();
    float acc = 0.f;
#pragma unroll 8
    for (int c = 0; c < 2 * H; ++c) acc = fmaf(cat[c], W_out[c * H + k], acc);
    wout[b * H + k] = tanhf(acc);
}

extern "C" void kernel_launch(void* const* d_in, const int* in_sizes, int n_in,
                              void* d_out, int out_size, void* d_ws, size_t ws_size,
                              hipStream_t stream) {
    const float* query = (const float*)d_in[0];
    const float* enc   = (const float*)d_in[1];
    const int*   lens  = (const int*)d_in[2];
    const float* W_h   = (const float*)d_in[3];
    const float* W_s   = (const float*)d_in[4];
    const float* v     = (const float*)d_in[5];
    const float* W_out = (const float*)d_in[6];

    float* out  = (float*)d_out;
    float* wout = out;          // B*H
    float* attn = out + B * H;  // B*S

    float* ws     = (float*)d_ws;
    float* qs     = ws + QS_OFF;
    float* scores = ws + SC_OFF;
    float* pc     = ws + PC_OFF;
    short* Wt     = (short*)(ws + PC_OFF);   // aliases pc: Wt used in scores (before pc written)

    qs_kernel<<<B, H, 0, stream>>>(query, W_s, qs);
    wt_prep<<<1024, 256, 0, stream>>>(W_h, Wt);
    scores_mfma_kernel<<<B * (S / BM), 256, 0, stream>>>(enc, Wt, v, lens, qs, scores);
    softmax_kernel<<<B, 256, 0, stream>>>(scores, lens, attn);
    ctx_partial_kernel<<<B * NCHUNK, 256, 0, stream>>>(enc, attn, lens, pc);
    out_kernel<<<B, H, 0, stream>>>(pc, query, W_out, lens, wout);
}

// Round 3
// 214.312 us; speedup vs baseline: 3.4930x; 1.7525x over previous
//
#include <hip/hip_runtime.h>
#include <math.h>

#define B 64
#define S 2048
#define H 512
#define BM 64

// workspace layout (floats)
#define QS_OFF 0                    // qs:     B*H
#define SC_OFF (B*H)                // scores: B*S
#define PC_OFF (B*H + B*S)          // pc:     B*NCHUNK*H  (Wt aliases this region, used before pc)
#define NCHUNK 32
#define CHUNK  64                   // S / NCHUNK

typedef __attribute__((ext_vector_type(8))) short short8;
typedef __attribute__((ext_vector_type(4))) float f32x4;

static __device__ __forceinline__ short f2bf(float f) {
    union { float f; unsigned u; } x; x.f = f;
    unsigned r = x.u + 0x7fffu + ((x.u >> 16) & 1u);   // RNE
    return (short)(r >> 16);
}

static __device__ __forceinline__ float ftanh(float x) {
    x = fminf(fmaxf(x, -30.f), 30.f);
    const float e = __builtin_amdgcn_exp2f(x * 2.8853900817779268f); // e^(2x)
    return (e - 1.f) * __builtin_amdgcn_rcpf(e + 1.f);
}

// ---------------- kernel 1: q_scores = query @ W_s (B,H) ----------------
__global__ __launch_bounds__(512) void qs_kernel(const float* __restrict__ query,
                                                 const float* __restrict__ W_s,
                                                 float* __restrict__ qs) {
    const int b = blockIdx.x, k = threadIdx.x;
    __shared__ float q[H];
    q[k] = query[b * H + k];
    __syncthreads();
    float acc = 0.f;
#pragma unroll 8
    for (int h = 0; h < H; ++h) acc = fmaf(q[h], W_s[h * H + k], acc);
    qs[b * H + k] = acc;
}

// -------- kernel 1b: W_h -> bf16 fragment-ordered Wt --------
// Wt[(((CB*16+kk)*4 + g)*16 + c)*8 + j] = bf16(W_h[(kk*32+g*8+j)*H + CB*16+c])
__global__ __launch_bounds__(256) void wt_prep(const float* __restrict__ W_h,
                                               short* __restrict__ Wt) {
    const int idx = blockIdx.x * 256 + threadIdx.x;       // 0 .. 262143
    const int j  = idx & 7;
    const int c  = (idx >> 3) & 15;
    const int g  = (idx >> 7) & 3;
    const int kk = (idx >> 9) & 15;
    const int CB = idx >> 13;
    const int k   = kk * 32 + g * 8 + j;
    const int col = CB * 16 + c;
    Wt[idx] = f2bf(W_h[k * H + col]);
}

// ------- kernel 2: scores = v . tanh(enc @ W_h + qs) — MFMA, BM=64, B-prefetch -------
__global__ __launch_bounds__(256, 2) void scores_mfma_kernel(const float* __restrict__ enc,
                                                             const short* __restrict__ Wt,
                                                             const float* __restrict__ v,
                                                             const int* __restrict__ lens,
                                                             const float* __restrict__ qs,
                                                             float* __restrict__ scores) {
    const int b = blockIdx.x >> 5;
    const int s0 = (blockIdx.x & 31) * BM;
    const int len = lens[b];
    if (s0 >= len) return;
    const int t = threadIdx.x;
    const int w = t >> 6, l = t & 63;
    const int g = l >> 4, c = l & 15;

    __shared__ short elds[BM * H];     // 64 KB, XOR-swizzled bf16 tile
    __shared__ float red[4][BM];

    // stage 64x512 fp32 -> bf16 into LDS (swizzled)
    {
        const float* src = enc + ((size_t)(b * S + s0)) * H;
#pragma unroll
        for (int i = 0; i < 16; ++i) {
            const int ch = i * 256 + t;
            const int row = ch >> 6;
            const int ks  = (ch & 63) * 8;
            const float4* p = (const float4*)(src + row * H + ks);
            const float4 f0 = p[0], f1 = p[1];
            short8 hv;
            hv[0] = f2bf(f0.x); hv[1] = f2bf(f0.y); hv[2] = f2bf(f0.z); hv[3] = f2bf(f0.w);
            hv[4] = f2bf(f1.x); hv[5] = f2bf(f1.y); hv[6] = f2bf(f1.z); hv[7] = f2bf(f1.w);
            const int byteoff = row * 1024 + ((ks * 2) ^ ((row & 7) << 4));
            *(short8*)((char*)elds + byteoff) = hv;
        }
    }
    __syncthreads();

    // per-wave B base: Wt + w*65536 + g*128 + c*8; frag(kk,cb) at + kk*512 + cb*8192
    const short* WtW = Wt + (size_t)w * 65536 + g * 128 + c * 8;
    const int abase = (g << 4); // koff contribution from g (bytes = g*16)

#define LOADB(buf, kk_)                                                        \
    {                                                                          \
        const short* wp_ = WtW + (kk_) * 512;                                  \
        _Pragma("unroll")                                                      \
        for (int cb = 0; cb < 8; ++cb) buf[cb] = *(const short8*)(wp_ + cb * 8192); \
    }

#define LOADA(af, kk_)                                                         \
    {                                                                          \
        const int koff_ = (kk_) * 64 + abase;                                  \
        _Pragma("unroll")                                                      \
        for (int rb = 0; rb < 4; ++rb) {                                       \
            const int r_ = rb * 16 + c;                                        \
            af[rb] = *(const short8*)((char*)elds + r_ * 1024 + (koff_ ^ ((c & 7) << 4))); \
        }                                                                      \
    }

#define DOMFMA(af, bf)                                                         \
    _Pragma("unroll")                                                          \
    for (int cb = 0; cb < 8; ++cb)                                             \
        _Pragma("unroll")                                                      \
        for (int rb = 0; rb < 4; ++rb)                                         \
            acc[rb][cb] = __builtin_amdgcn_mfma_f32_16x16x32_bf16(af[rb], bf[cb], acc[rb][cb], 0, 0, 0);

    f32x4 acc[4][8];
    const f32x4 z = {0.f, 0.f, 0.f, 0.f};
#pragma unroll
    for (int rb = 0; rb < 4; ++rb)
#pragma unroll
        for (int cb = 0; cb < 8; ++cb) acc[rb][cb] = z;

    short8 bufA[8], bufB[8], afr[4];
    LOADB(bufA, 0)
#pragma unroll
    for (int kk = 0; kk < 16; kk += 2) {
        LOADB(bufB, kk + 1)
        LOADA(afr, kk)
        DOMFMA(afr, bufA)
        if (kk + 2 < 16) LOADB(bufA, kk + 2)
        LOADA(afr, kk + 1)
        DOMFMA(afr, bufB)
    }

    // epilogue: p[row] = sum_col v[col] * tanh(escore + qs[col])
    float part[4][4];
#pragma unroll
    for (int rb = 0; rb < 4; ++rb)
#pragma unroll
        for (int r = 0; r < 4; ++r) part[rb][r] = 0.f;

#pragma unroll
    for (int cb = 0; cb < 8; ++cb) {
        const int col = w * 128 + cb * 16 + c;
        const float vc = v[col];
        const float qc = qs[b * H + col];
#pragma unroll
        for (int rb = 0; rb < 4; ++rb)
#pragma unroll
            for (int r = 0; r < 4; ++r)
                part[rb][r] += vc * ftanh(acc[rb][cb][r] + qc);
    }
#pragma unroll
    for (int m = 1; m < 16; m <<= 1)
#pragma unroll
        for (int rb = 0; rb < 4; ++rb)
#pragma unroll
            for (int r = 0; r < 4; ++r)
                part[rb][r] += __shfl_xor(part[rb][r], m);
    if (c == 0) {
#pragma unroll
        for (int rb = 0; rb < 4; ++rb)
#pragma unroll
            for (int r = 0; r < 4; ++r)
                red[w][rb * 16 + g * 4 + r] = part[rb][r];
    }
    __syncthreads();
    if (t < BM) scores[b * S + s0 + t] = red[0][t] + red[1][t] + red[2][t] + red[3][t];
}

// ---------------- kernel 3: masked softmax over S, write attn ----------------
__global__ __launch_bounds__(256) void softmax_kernel(const float* __restrict__ scores,
                                                      const int* __restrict__ lens,
                                                      float* __restrict__ attn) {
    const int b = blockIdx.x, t = threadIdx.x;
    const int len = lens[b];
    const int wave = t >> 6, lane = t & 63;
    __shared__ float red[4];

    float vals[8];
    float m = -INFINITY;
#pragma unroll
    for (int i = 0; i < 8; ++i) {
        const int s = i * 256 + t;
        vals[i] = (s < len) ? scores[b * S + s] : -INFINITY;
        m = fmaxf(m, vals[i]);
    }
#pragma unroll
    for (int off = 32; off > 0; off >>= 1) m = fmaxf(m, __shfl_down(m, off));
    if (lane == 0) red[wave] = m;
    __syncthreads();
    m = fmaxf(fmaxf(red[0], red[1]), fmaxf(red[2], red[3]));
    __syncthreads();

    float e[8];
    float sum = 0.f;
#pragma unroll
    for (int i = 0; i < 8; ++i) {
        const int s = i * 256 + t;
        e[i] = (s < len) ? expf(vals[i] - m) : 0.f;
        sum += e[i];
    }
#pragma unroll
    for (int off = 32; off > 0; off >>= 1) sum += __shfl_down(sum, off);
    if (lane == 0) red[wave] = sum;
    __syncthreads();
    const float inv = 1.f / (red[0] + red[1] + red[2] + red[3]);
#pragma unroll
    for (int i = 0; i < 8; ++i) attn[b * S + i * 256 + t] = e[i] * inv;
}

// -------- kernel 4a: partial context sums over s-chunks (masked skipped) --------
__global__ __launch_bounds__(256) void ctx_partial_kernel(const float* __restrict__ enc,
                                                          const float* __restrict__ attn,
                                                          const int* __restrict__ lens,
                                                          float* __restrict__ pc) {
    const int b = blockIdx.x >> 5, c = blockIdx.x & 31;
    const int len = lens[b];
    const int sbase = c * CHUNK;
    if (sbase >= len) return;
    const int ns = min(CHUNK, len - sbase);
    const int t = threadIdx.x;

    __shared__ float alds[CHUNK];
    if (t < CHUNK) alds[t] = (t < ns) ? attn[b * S + sbase + t] : 0.f;
    __syncthreads();

    const float2* e2 = (const float2*)(enc + (size_t)(b * S + sbase) * H);
    float2 acc = make_float2(0.f, 0.f);
    for (int s = 0; s < ns; ++s) {
        const float a = alds[s];
        const float2 e = e2[s * 256 + t];
        acc.x = fmaf(a, e.x, acc.x);
        acc.y = fmaf(a, e.y, acc.y);
    }
    ((float2*)(pc + (size_t)(b * NCHUNK + c) * H))[t] = acc;
}

// ------ kernel 4b: context reduce + w_out = tanh([ctx, q] @ W_out) ------
__global__ __launch_bounds__(512) void out_kernel(const float* __restrict__ pc,
                                                  const float* __restrict__ query,
                                                  const float* __restrict__ W_out,
                                                  const int* __restrict__ lens,
                                                  float* __restrict__ wout) {
    const int b = blockIdx.x, k = threadIdx.x;
    const int len = lens[b];
    const int nch = (len + CHUNK - 1) / CHUNK;
    __shared__ float cat[2 * H];
    float ctx = 0.f;
    for (int c = 0; c < nch; ++c) ctx += pc[(size_t)(b * NCHUNK + c) * H + k];
    cat[k] = ctx;
    cat[H + k] = query[b * H + k];
    __syncthreads();
    float acc = 0.f;
#pragma unroll 8
    for (int c = 0; c < 2 * H; ++c) acc = fmaf(cat[c], W_out[c * H + k], acc);
    wout[b * H + k] = tanhf(acc);
}

extern "C" void kernel_launch(void* const* d_in, const int* in_sizes, int n_in,
                              void* d_out, int out_size, void* d_ws, size_t ws_size,
                              hipStream_t stream) {
    const float* query = (const float*)d_in[0];
    const float* enc   = (const float*)d_in[1];
    const int*   lens  = (const int*)d_in[2];
    const float* W_h   = (const float*)d_in[3];
    const float* W_s   = (const float*)d_in[4];
    const float* v     = (const float*)d_in[5];
    const float* W_out = (const float*)d_in[6];

    float* out  = (float*)d_out;
    float* wout = out;          // B*H
    float* attn = out + B * H;  // B*S

    float* ws     = (float*)d_ws;
    float* qs     = ws + QS_OFF;
    float* scores = ws + SC_OFF;
    float* pc     = ws + PC_OFF;
    short* Wt     = (short*)(ws + PC_OFF);   // aliases pc: Wt used in scores (before pc written)

    qs_kernel<<<B, H, 0, stream>>>(query, W_s, qs);
    wt_prep<<<1024, 256, 0, stream>>>(W_h, Wt);
    scores_mfma_kernel<<<B * (S / BM), 256, 0, stream>>>(enc, Wt, v, lens, qs, scores);
    softmax_kernel<<<B, 256, 0, stream>>>(scores, lens, attn);
    ctx_partial_kernel<<<B * NCHUNK, 256, 0, stream>>>(enc, attn, lens, pc);
    out_kernel<<<B, H, 0, stream>>>(pc, query, W_out, lens, wout);
}